// Round 9
// baseline (219.367 us; speedup 1.0000x reference)
//
#include <hip/hip_runtime.h>
#include <hip/hip_fp16.h>

#define N_NODES 50000
#define N_EDGES 800000
#define DIM 64
#define N_GRAPH 512
#define N_CLASS 10
#define SCHUNK 512
#define NSCB ((N_NODES + SCHUNK - 1) / SCHUNK)   // 98 blocks per branch
#define NTILES (N_NODES / 16)                     // 3125 MFMA row-tiles
#define NSHARD 8

typedef _Float16 f16;
typedef f16 f16x8 __attribute__((ext_vector_type(8)));
typedef float f32x4 __attribute__((ext_vector_type(4)));

// ---------------- sharded degree + per-edge local rank + x->fp16 ----------------
// shard = blockIdx.x & 7 ~ XCD id (dispatch round-robin heuristic; perf-only).
// rank_*[e] = position within (shard, dst) bucket -> fill needs NO atomics.
__global__ void degrank_conv_kernel(const int* __restrict__ dst_sc,
                                    const int* __restrict__ dst_fc,
                                    int* __restrict__ deg8_sc,
                                    int* __restrict__ deg8_fc,
                                    unsigned short* __restrict__ rank_sc,
                                    unsigned short* __restrict__ rank_fc,
                                    const float* __restrict__ x,
                                    __half* __restrict__ xh) {
    int i = blockIdx.x * blockDim.x + threadIdx.x;
    int shard = blockIdx.x & (NSHARD - 1);
    if (i < N_EDGES) {
        rank_sc[i] = (unsigned short)atomicAdd(&deg8_sc[shard * N_NODES + dst_sc[i]], 1);
        rank_fc[i] = (unsigned short)atomicAdd(&deg8_fc[shard * N_NODES + dst_fc[i]], 1);
        float4 v = *(const float4*)(x + (size_t)i * 4);
        union { __half2 h2[2]; float2 f2; } u;
        u.h2[0] = __floats2half2_rn(v.x, v.y);
        u.h2[1] = __floats2half2_rn(v.z, v.w);
        *(float2*)(xh + (size_t)i * 4) = u.f2;
    }
}

// ---------------- reduce shards: total degree + per-shard exclusive base ----------------
__global__ void reduce8_kernel(const int* __restrict__ deg8_sc, const int* __restrict__ deg8_fc,
                               int* __restrict__ deg_sc, int* __restrict__ deg_fc,
                               int* __restrict__ base8_sc, int* __restrict__ base8_fc) {
    int i = blockIdx.x * blockDim.x + threadIdx.x;
    if (i >= N_NODES) return;
    const int* d8 = blockIdx.y ? deg8_fc : deg8_sc;
    int* dg       = blockIdx.y ? deg_fc : deg_sc;
    int* b8       = blockIdx.y ? base8_fc : base8_sc;
    int run = 0;
#pragma unroll
    for (int s = 0; s < NSHARD; ++s) {
        b8[s * N_NODES + i] = run;
        run += d8[s * N_NODES + i];
    }
    dg[i] = run;
}

// ---------------- hierarchical scan ----------------
__global__ void scanA_kernel(const int* __restrict__ deg_sc,
                             const int* __restrict__ deg_fc,
                             int* __restrict__ partial) {
    const int* deg = blockIdx.y ? deg_fc : deg_sc;
    int base = blockIdx.x * SCHUNK;
    int t = threadIdx.x;
    int s = 0;
    int i0 = base + t, i1 = base + t + 256;
    if (i0 < N_NODES) s += deg[i0];
    if (i1 < N_NODES) s += deg[i1];
    __shared__ int red[256];
    red[t] = s;
    __syncthreads();
    for (int off = 128; off > 0; off >>= 1) {
        if (t < off) red[t] += red[t + off];
        __syncthreads();
    }
    if (t == 0) partial[blockIdx.y * NSCB + blockIdx.x] = red[0];
}

__global__ void scanB_kernel(int* __restrict__ partial) {
    __shared__ int s[2 * NSCB];
    int t = threadIdx.x;
    for (int k = t; k < 2 * NSCB; k += blockDim.x) s[k] = partial[k];
    __syncthreads();
    if (t < 2) {
        int* p = s + t * NSCB;
        int run = 0;
        for (int i = 0; i < NSCB; ++i) { int v = p[i]; p[i] = run; run += v; }
    }
    __syncthreads();
    for (int k = t; k < 2 * NSCB; k += blockDim.x) partial[k] = s[k];
}

__global__ void scanC_kernel(const int* __restrict__ deg_sc,
                             const int* __restrict__ deg_fc,
                             const int* __restrict__ partial,
                             int* __restrict__ row_sc, int* __restrict__ row_fc,
                             float* __restrict__ inv_sc, float* __restrict__ inv_fc) {
    const int* deg = blockIdx.y ? deg_fc : deg_sc;
    int* row = blockIdx.y ? row_fc : row_sc;
    float* inv = blockIdx.y ? inv_fc : inv_sc;
    int base = blockIdx.x * SCHUNK;
    int t = threadIdx.x;
    int i0 = base + 2 * t, i1 = i0 + 1;
    int d0 = (i0 < N_NODES) ? deg[i0] : 0;
    int d1 = (i1 < N_NODES) ? deg[i1] : 0;
    __shared__ int s[256];
    s[t] = d0 + d1;
    __syncthreads();
    for (int off = 1; off < 256; off <<= 1) {
        int v = (t >= off) ? s[t - off] : 0;
        __syncthreads();
        s[t] += v;
        __syncthreads();
    }
    int pre = (t == 0) ? 0 : s[t - 1];
    int blockbase = partial[blockIdx.y * NSCB + blockIdx.x];
    int r0 = blockbase + pre;
    if (i0 < N_NODES) { row[i0] = r0;      inv[i0] = 1.0f / fmaxf((float)d0, 1.0f); }
    if (i1 < N_NODES) { row[i1] = r0 + d0; inv[i1] = 1.0f / fmaxf((float)d1, 1.0f); }
    if (blockIdx.x == 0 && t == 0) row[N_NODES] = N_EDGES;
}

// ---------------- atomic-free counting-sort fill (sharded ranks) ----------------
__global__ void fill2_kernel(const int* __restrict__ src_sc, const int* __restrict__ dst_sc,
                             const unsigned short* __restrict__ rank_sc,
                             const int* __restrict__ row_sc, const int* __restrict__ base8_sc,
                             unsigned short* __restrict__ sorted_sc,
                             const int* __restrict__ src_fc, const int* __restrict__ dst_fc,
                             const unsigned short* __restrict__ rank_fc,
                             const int* __restrict__ row_fc, const int* __restrict__ base8_fc,
                             unsigned short* __restrict__ sorted_fc) {
    int e = blockIdx.x * blockDim.x + threadIdx.x;
    if (e >= N_EDGES) return;
    int shard = blockIdx.x & (NSHARD - 1);   // must match degrank's mapping
    const int *src, *dst, *row, *base8;
    const unsigned short* rank;
    unsigned short* sorted;
    if (blockIdx.y == 0) { src = src_sc; dst = dst_sc; rank = rank_sc; row = row_sc; base8 = base8_sc; sorted = sorted_sc; }
    else                 { src = src_fc; dst = dst_fc; rank = rank_fc; row = row_fc; base8 = base8_fc; sorted = sorted_fc; }
    int d = dst[e];
    int pos = row[d] + base8[shard * N_NODES + d] + (int)rank[e];
    sorted[pos] = (unsigned short)src[e];
}

// ---------------- pure gather-aggregate (fp16 in/out, mean folded) ----------------
// block = 256 = 4 waves = 4 nodes; wave = 8 edge-groups x 8 lanes x half8 (16B).
__global__ void agg_kernel(const int* __restrict__ row_a, const unsigned short* __restrict__ sorted_a,
                           const float* __restrict__ inv_a, const __half* __restrict__ in_a,
                           __half* __restrict__ out_a,
                           const int* __restrict__ row_b, const unsigned short* __restrict__ sorted_b,
                           const float* __restrict__ inv_b, const __half* __restrict__ in_b,
                           __half* __restrict__ out_b) {
    const int* row;  const unsigned short* sorted; const float* inv;
    const f16* in;   f16* out;
    if (blockIdx.y == 0) { row = row_a; sorted = sorted_a; inv = inv_a; in = (const f16*)in_a; out = (f16*)out_a; }
    else                 { row = row_b; sorted = sorted_b; inv = inv_b; in = (const f16*)in_b; out = (f16*)out_b; }

    int t = threadIdx.x;
    int n = blockIdx.x * 4 + (t >> 6);
    if (n >= N_NODES) return;
    int lane = t & 63;
    int eg = lane >> 3;            // edge slot within group-of-8
    int c  = (lane & 7) << 3;      // feature chunk base (8 halves)

    int beg = row[n], end = row[n + 1];
    float iv = inv[n];
    float acc[8] = {0.f, 0.f, 0.f, 0.f, 0.f, 0.f, 0.f, 0.f};
    int k = beg;
    for (; k + 16 <= end; k += 16) {           // 16 edges/wave-iter, 2 half8 in flight
        int s0 = sorted[k + eg];
        int s1 = sorted[k + 8 + eg];
        f16x8 v0 = *(const f16x8*)(in + (size_t)s0 * DIM + c);
        f16x8 v1 = *(const f16x8*)(in + (size_t)s1 * DIM + c);
#pragma unroll
        for (int m = 0; m < 8; ++m) acc[m] += (float)v0[m] + (float)v1[m];
    }
    if (k + 8 <= end) {
        int s0 = sorted[k + eg];
        f16x8 v0 = *(const f16x8*)(in + (size_t)s0 * DIM + c);
#pragma unroll
        for (int m = 0; m < 8; ++m) acc[m] += (float)v0[m];
        k += 8;
    }
    if (k + eg < end) {                        // tail (<8 edges)
        f16x8 v0 = *(const f16x8*)(in + (size_t)sorted[k + eg] * DIM + c);
#pragma unroll
        for (int m = 0; m < 8; ++m) acc[m] += (float)v0[m];
    }
#pragma unroll
    for (int m = 0; m < 8; ++m) {
        acc[m] += __shfl_xor(acc[m], 8, 64);
        acc[m] += __shfl_xor(acc[m], 16, 64);
        acc[m] += __shfl_xor(acc[m], 32, 64);
    }
    if (eg == 0) {
        f16x8 r;
#pragma unroll
        for (int m = 0; m < 8; ++m) r[m] = (f16)(acc[m] * iv);
        *(f16x8*)(out + (size_t)n * DIM + c) = r;
    }
}

// ---------------- W -> MFMA B-fragment layout (fp16), 4 matrices ----------------
__global__ void wfrag_kernel(const float* __restrict__ W0, const float* __restrict__ W1,
                             f16* __restrict__ wfrag) {
    int mat = blockIdx.x;                       // 0:W0L0 1:W0L1 2:W1L0 3:W1L1
    const float* W = (mat & 2) ? W1 : W0;
    if (mat & 1) W += DIM * DIM;
    int t = threadIdx.x;
    for (int idx = t; idx < 4096; idx += 256) {
        int ct = idx >> 10, kk = (idx >> 9) & 1, l = (idx >> 3) & 63, i = idx & 7;
        int k = kk * 32 + (l >> 4) * 8 + i;
        int col = ct * 16 + (l & 15);
        wfrag[mat * 4096 + idx] = (f16)W[k * DIM + col];
    }
}

// ---------------- MFMA GEMM: out = relu(A @ W + b), fp16 in/out ----------------
__global__ void gemm_kernel(const __half* __restrict__ A_a, const f16* __restrict__ wf_a,
                            const float* __restrict__ bias_a, __half* __restrict__ out_a,
                            const __half* __restrict__ A_b, const f16* __restrict__ wf_b,
                            const float* __restrict__ bias_b, __half* __restrict__ out_b) {
    const f16* A; const f16* wf; const float* bias; f16* out;
    if (blockIdx.y == 0) { A = (const f16*)A_a; wf = wf_a; bias = bias_a; out = (f16*)out_a; }
    else                 { A = (const f16*)A_b; wf = wf_b; bias = bias_b; out = (f16*)out_b; }

    int t = threadIdx.x, w = t >> 6, l = t & 63;
    int tile = blockIdx.x * 4 + w;
    if (tile >= NTILES) return;
    int g = l >> 4, c = l & 15;

    const f16* arow = A + ((size_t)tile * 16 + c) * DIM + 8 * g;
    f16x8 a0 = *(const f16x8*)(arow);
    f16x8 a1 = *(const f16x8*)(arow + 32);

#pragma unroll
    for (int ct = 0; ct < 4; ++ct) {
        f16x8 b0 = *(const f16x8*)(wf + ((ct * 2 + 0) * 64 + l) * 8);
        f16x8 b1 = *(const f16x8*)(wf + ((ct * 2 + 1) * 64 + l) * 8);
        f32x4 acc = {0.f, 0.f, 0.f, 0.f};
        acc = __builtin_amdgcn_mfma_f32_16x16x32_f16(a0, b0, acc, 0, 0, 0);
        acc = __builtin_amdgcn_mfma_f32_16x16x32_f16(a1, b1, acc, 0, 0, 0);
        float bs = bias[ct * 16 + c];
#pragma unroll
        for (int i = 0; i < 4; ++i) {
            float v = fmaxf(acc[i] + bs, 0.0f);
            out[((size_t)tile * 16 + 4 * g + i) * DIM + ct * 16 + c] = (f16)v;
        }
    }
}

// ---------------- per-graph projection ----------------
__global__ void graph_proj_kernel(const __half* __restrict__ x0, const __half* __restrict__ x1,
                                  const float* __restrict__ Wout, const float* __restrict__ bout,
                                  const int* __restrict__ batch, float* __restrict__ out) {
    int g = blockIdx.x;
    __shared__ int bounds[2];
    __shared__ float hs[4][DIM];
    int t = threadIdx.x;
    if (t < 2) {
        int target = g + t;
        int lo = 0, hi = N_NODES;
        while (lo < hi) { int mid = (lo + hi) >> 1; if (batch[mid] < target) lo = mid + 1; else hi = mid; }
        bounds[t] = lo;
    }
    __syncthreads();
    int beg = bounds[0], end = bounds[1];
    int w = t >> 6, j = t & 63;
    float s = 0.0f;
    for (int n = beg + w; n < end; n += 4)
        s += __half2float(x0[(size_t)n * DIM + j]) + __half2float(x1[(size_t)n * DIM + j]);
    hs[w][j] = s;
    __syncthreads();
    if (t < DIM) hs[0][t] = (hs[0][t] + hs[1][t] + hs[2][t] + hs[3][t]) * 0.5f;
    __syncthreads();
    if (t < N_CLASS) {
        int cnt = end - beg;
        float acc = 0.0f;
#pragma unroll
        for (int d = 0; d < DIM; ++d) acc += hs[0][d] * Wout[d * N_CLASS + t];
        out[g * N_CLASS + t] = (cnt > 0) ? (acc / (float)cnt + bout[t]) : 0.0f;
    }
}

extern "C" void kernel_launch(void* const* d_in, const int* in_sizes, int n_in,
                              void* d_out, int out_size, void* d_ws, size_t ws_size,
                              hipStream_t stream) {
    const float* x    = (const float*)d_in[0];
    const float* W0   = (const float*)d_in[1];
    const float* b0   = (const float*)d_in[2];
    const float* W1   = (const float*)d_in[3];
    const float* b1   = (const float*)d_in[4];
    const float* Wout = (const float*)d_in[5];
    const float* bout = (const float*)d_in[6];
    const int* ei_sc  = (const int*)d_in[7];
    const int* ei_fc  = (const int*)d_in[8];
    const int* batch  = (const int*)d_in[9];

    const int* src_sc = ei_sc;
    const int* dst_sc = ei_sc + N_EDGES;
    const int* src_fc = ei_fc;
    const int* dst_fc = ei_fc + N_EDGES;

    // ---- workspace layout (byte-based) ----
    char* ws = (char*)d_ws;
    size_t off = 0;
    auto alloc = [&](size_t bytes) { void* p = ws + off; off += (bytes + 15) & ~size_t(15); return p; };
    __half* xh   = (__half*)alloc((size_t)N_NODES * DIM * 2);
    __half* As_  = (__half*)alloc((size_t)N_NODES * DIM * 2);  // agg sc  | aliased: base8_sc
    __half* Af_  = (__half*)alloc((size_t)N_NODES * DIM * 2);  // agg fc  | aliased: base8_fc
    __half* Hs_  = (__half*)alloc((size_t)N_NODES * DIM * 2);  // hidden sc | aliased: deg8_sc
    __half* Hf_  = (__half*)alloc((size_t)N_NODES * DIM * 2);  // hidden fc | aliased: deg8_fc
    f16*   wfrag = (f16*)alloc(4 * 4096 * 2);
    float* inv_sc = (float*)alloc(N_NODES * 4);
    float* inv_fc = (float*)alloc(N_NODES * 4);
    int*   deg_sc = (int*)alloc(N_NODES * 4);
    int*   deg_fc = (int*)alloc(N_NODES * 4);
    int*   row_sc = (int*)alloc((N_NODES + 1) * 4);
    int*   row_fc = (int*)alloc((N_NODES + 1) * 4);
    int*   partial = (int*)alloc(2 * NSCB * 4);
    unsigned short* rank_sc = (unsigned short*)alloc((size_t)N_EDGES * 2);
    unsigned short* rank_fc = (unsigned short*)alloc((size_t)N_EDGES * 2);
    unsigned short* sorted_sc = (unsigned short*)alloc((size_t)N_EDGES * 2);
    unsigned short* sorted_fc = (unsigned short*)alloc((size_t)N_EDGES * 2);

    // shard histograms/bases alias buffers that are dead until after fill2
    int* deg8_sc  = (int*)Hs_;   // 8*N ints = 1.6 MB <= 6.4 MB
    int* deg8_fc  = (int*)Hf_;
    int* base8_sc = (int*)As_;
    int* base8_fc = (int*)Af_;

    const int BLK = 256;
    dim3 blk(BLK);
    int grid_E  = (N_EDGES + BLK - 1) / BLK;
    int grid_N4 = (N_NODES + 3) / 4;
    int grid_N  = (N_NODES + BLK - 1) / BLK;
    int grid_G  = (NTILES + 3) / 4;

    // ---- CSR build + x->fp16 + W fragments ----
    hipMemsetAsync(deg8_sc, 0, (size_t)NSHARD * N_NODES * 4, stream);
    hipMemsetAsync(deg8_fc, 0, (size_t)NSHARD * N_NODES * 4, stream);
    wfrag_kernel<<<4, blk, 0, stream>>>(W0, W1, wfrag);
    degrank_conv_kernel<<<grid_E, blk, 0, stream>>>(dst_sc, dst_fc, deg8_sc, deg8_fc,
                                                    rank_sc, rank_fc, x, xh);
    reduce8_kernel<<<dim3(grid_N, 2), blk, 0, stream>>>(deg8_sc, deg8_fc,
                                                        deg_sc, deg_fc,
                                                        base8_sc, base8_fc);
    scanA_kernel<<<dim3(NSCB, 2), blk, 0, stream>>>(deg_sc, deg_fc, partial);
    scanB_kernel<<<1, 64, 0, stream>>>(partial);
    scanC_kernel<<<dim3(NSCB, 2), blk, 0, stream>>>(deg_sc, deg_fc, partial,
                                                    row_sc, row_fc, inv_sc, inv_fc);
    fill2_kernel<<<dim3(grid_E, 2), blk, 0, stream>>>(
        src_sc, dst_sc, rank_sc, row_sc, base8_sc, sorted_sc,
        src_fc, dst_fc, rank_fc, row_fc, base8_fc, sorted_fc);

    // ---- layer 0: agg (xh -> As,Af), gemm (-> Hs,Hf) ----
    agg_kernel<<<dim3(grid_N4, 2), blk, 0, stream>>>(
        row_sc, sorted_sc, inv_sc, xh, As_,
        row_fc, sorted_fc, inv_fc, xh, Af_);
    gemm_kernel<<<dim3(grid_G, 2), blk, 0, stream>>>(
        As_, wfrag + 0 * 4096, b0, Hs_,
        Af_, wfrag + 2 * 4096, b1, Hf_);

    // ---- layer 1: agg (Hs,Hf -> As,Af), gemm (-> Hs,Hf) ----
    agg_kernel<<<dim3(grid_N4, 2), blk, 0, stream>>>(
        row_sc, sorted_sc, inv_sc, Hs_, As_,
        row_fc, sorted_fc, inv_fc, Hf_, Af_);
    gemm_kernel<<<dim3(grid_G, 2), blk, 0, stream>>>(
        As_, wfrag + 1 * 4096, b0 + DIM, Hs_,
        Af_, wfrag + 3 * 4096, b1 + DIM, Hf_);

    // ---- per-graph projection ----
    graph_proj_kernel<<<N_GRAPH, blk, 0, stream>>>(Hs_, Hf_, Wout, bout, batch,
                                                   (float*)d_out);
}

// Round 10
// 175.415 us; speedup vs baseline: 1.2506x; 1.2506x over previous
//
#include <hip/hip_runtime.h>
#include <hip/hip_fp16.h>

#define N_NODES 50000
#define N_EDGES 800000
#define DIM 64
#define N_GRAPH 512
#define N_CLASS 10
#define SCHUNK 512
#define NSCB ((N_NODES + SCHUNK - 1) / SCHUNK)   // 98 blocks per branch
#define NTILES (N_NODES / 16)                     // 3125 MFMA row-tiles
#define NB 64                                     // histogram blocks per branch
#define EPB (N_EDGES / NB)                        // 12500 edges per block
#define NHALF (N_NODES / 2)                       // 25000 packed counters

typedef _Float16 f16;
typedef f16 f16x8 __attribute__((ext_vector_type(8)));
typedef float f32x4 __attribute__((ext_vector_type(4)));

// ---------------- x -> fp16 ----------------
__global__ void conv_kernel(const float* __restrict__ x, __half* __restrict__ xh) {
    int i = blockIdx.x * blockDim.x + threadIdx.x;
    if (i < N_NODES * DIM / 4) {
        float4 v = *(const float4*)(x + (size_t)i * 4);
        union { __half2 h2[2]; float2 f2; } u;
        u.h2[0] = __floats2half2_rn(v.x, v.y);
        u.h2[1] = __floats2half2_rn(v.z, v.w);
        *(float2*)(xh + (size_t)i * 4) = u.f2;
    }
}

// ---------------- LDS histogram + per-edge block-local rank ----------------
// Each block owns a contiguous 12500-edge slice; full 50K-node histogram lives
// in LDS as 25000 dwords (two 16-bit counters per dword). NO global atomics.
__global__ void __launch_bounds__(1024)
hist_kernel(const int* __restrict__ dst_sc, const int* __restrict__ dst_fc,
            unsigned short* __restrict__ rank_sc, unsigned short* __restrict__ rank_fc,
            unsigned int* __restrict__ cnt_sc, unsigned int* __restrict__ cnt_fc) {
    extern __shared__ unsigned int h[];               // NHALF dwords = 100 KB
    const int* dst = blockIdx.y ? dst_fc : dst_sc;
    unsigned short* rank = blockIdx.y ? rank_fc : rank_sc;
    unsigned int* cnt = blockIdx.y ? cnt_fc : cnt_sc;
    int t = threadIdx.x;
    for (int i = t; i < NHALF; i += 1024) h[i] = 0u;
    __syncthreads();
    int base = blockIdx.x * EPB;
    for (int e = base + t; e < base + EPB; e += 1024) {
        int d = dst[e];
        unsigned sh = (d & 1) << 4;
        unsigned old = atomicAdd(&h[d >> 1], 1u << sh);
        rank[e] = (unsigned short)((old >> sh) & 0xffffu);
    }
    __syncthreads();
    unsigned int* out = cnt + (size_t)blockIdx.x * NHALF;
    for (int i = t; i < NHALF; i += 1024) out[i] = h[i];
}

// ---------------- combine per-block counts -> deg + per-block base ----------------
__global__ void combine_kernel(const unsigned int* __restrict__ cnt_sc,
                               const unsigned int* __restrict__ cnt_fc,
                               unsigned short* __restrict__ base_sc,
                               unsigned short* __restrict__ base_fc,
                               int* __restrict__ deg_sc, int* __restrict__ deg_fc) {
    int n = blockIdx.x * blockDim.x + threadIdx.x;
    if (n >= N_NODES) return;
    const unsigned int* cnt = blockIdx.y ? cnt_fc : cnt_sc;
    unsigned short* bs      = blockIdx.y ? base_fc : base_sc;
    int* dg                 = blockIdx.y ? deg_fc : deg_sc;
    unsigned sh = (n & 1) << 4;
    int idx = n >> 1;
    int run = 0;
#pragma unroll 8
    for (int b = 0; b < NB; ++b) {
        bs[(size_t)b * N_NODES + n] = (unsigned short)run;
        run += (cnt[(size_t)b * NHALF + idx] >> sh) & 0xffffu;
    }
    dg[n] = run;
}

// ---------------- hierarchical scan ----------------
__global__ void scanA_kernel(const int* __restrict__ deg_sc,
                             const int* __restrict__ deg_fc,
                             int* __restrict__ partial) {
    const int* deg = blockIdx.y ? deg_fc : deg_sc;
    int base = blockIdx.x * SCHUNK;
    int t = threadIdx.x;
    int s = 0;
    int i0 = base + t, i1 = base + t + 256;
    if (i0 < N_NODES) s += deg[i0];
    if (i1 < N_NODES) s += deg[i1];
    __shared__ int red[256];
    red[t] = s;
    __syncthreads();
    for (int off = 128; off > 0; off >>= 1) {
        if (t < off) red[t] += red[t + off];
        __syncthreads();
    }
    if (t == 0) partial[blockIdx.y * NSCB + blockIdx.x] = red[0];
}

__global__ void scanB_kernel(int* __restrict__ partial) {
    __shared__ int s[2 * NSCB];
    int t = threadIdx.x;
    for (int k = t; k < 2 * NSCB; k += blockDim.x) s[k] = partial[k];
    __syncthreads();
    if (t < 2) {
        int* p = s + t * NSCB;
        int run = 0;
        for (int i = 0; i < NSCB; ++i) { int v = p[i]; p[i] = run; run += v; }
    }
    __syncthreads();
    for (int k = t; k < 2 * NSCB; k += blockDim.x) partial[k] = s[k];
}

__global__ void scanC_kernel(const int* __restrict__ deg_sc,
                             const int* __restrict__ deg_fc,
                             const int* __restrict__ partial,
                             int* __restrict__ row_sc, int* __restrict__ row_fc,
                             float* __restrict__ inv_sc, float* __restrict__ inv_fc) {
    const int* deg = blockIdx.y ? deg_fc : deg_sc;
    int* row = blockIdx.y ? row_fc : row_sc;
    float* inv = blockIdx.y ? inv_fc : inv_sc;
    int base = blockIdx.x * SCHUNK;
    int t = threadIdx.x;
    int i0 = base + 2 * t, i1 = i0 + 1;
    int d0 = (i0 < N_NODES) ? deg[i0] : 0;
    int d1 = (i1 < N_NODES) ? deg[i1] : 0;
    __shared__ int s[256];
    s[t] = d0 + d1;
    __syncthreads();
    for (int off = 1; off < 256; off <<= 1) {
        int v = (t >= off) ? s[t - off] : 0;
        __syncthreads();
        s[t] += v;
        __syncthreads();
    }
    int pre = (t == 0) ? 0 : s[t - 1];
    int blockbase = partial[blockIdx.y * NSCB + blockIdx.x];
    int r0 = blockbase + pre;
    if (i0 < N_NODES) { row[i0] = r0;      inv[i0] = 1.0f / fmaxf((float)d0, 1.0f); }
    if (i1 < N_NODES) { row[i1] = r0 + d0; inv[i1] = 1.0f / fmaxf((float)d1, 1.0f); }
    if (blockIdx.x == 0 && t == 0) row[N_NODES] = N_EDGES;
}

// ---------------- atomic-free counting-sort fill ----------------
__global__ void fill3_kernel(const int* __restrict__ src_sc, const int* __restrict__ dst_sc,
                             const unsigned short* __restrict__ rank_sc,
                             const int* __restrict__ row_sc,
                             const unsigned short* __restrict__ base_sc,
                             unsigned short* __restrict__ sorted_sc,
                             const int* __restrict__ src_fc, const int* __restrict__ dst_fc,
                             const unsigned short* __restrict__ rank_fc,
                             const int* __restrict__ row_fc,
                             const unsigned short* __restrict__ base_fc,
                             unsigned short* __restrict__ sorted_fc) {
    int e = blockIdx.x * blockDim.x + threadIdx.x;
    if (e >= N_EDGES) return;
    int b = e / EPB;                                  // block that ranked this edge
    const int *src, *dst, *row;
    const unsigned short *rank, *base;
    unsigned short* sorted;
    if (blockIdx.y == 0) { src = src_sc; dst = dst_sc; rank = rank_sc; row = row_sc; base = base_sc; sorted = sorted_sc; }
    else                 { src = src_fc; dst = dst_fc; rank = rank_fc; row = row_fc; base = base_fc; sorted = sorted_fc; }
    int d = dst[e];
    int pos = row[d] + (int)base[(size_t)b * N_NODES + d] + (int)rank[e];
    sorted[pos] = (unsigned short)src[e];
}

// ---------------- pure gather-aggregate (fp16 in/out, mean folded) ----------------
__global__ void agg_kernel(const int* __restrict__ row_a, const unsigned short* __restrict__ sorted_a,
                           const float* __restrict__ inv_a, const __half* __restrict__ in_a,
                           __half* __restrict__ out_a,
                           const int* __restrict__ row_b, const unsigned short* __restrict__ sorted_b,
                           const float* __restrict__ inv_b, const __half* __restrict__ in_b,
                           __half* __restrict__ out_b) {
    const int* row;  const unsigned short* sorted; const float* inv;
    const f16* in;   f16* out;
    if (blockIdx.y == 0) { row = row_a; sorted = sorted_a; inv = inv_a; in = (const f16*)in_a; out = (f16*)out_a; }
    else                 { row = row_b; sorted = sorted_b; inv = inv_b; in = (const f16*)in_b; out = (f16*)out_b; }

    int t = threadIdx.x;
    int n = blockIdx.x * 4 + (t >> 6);
    if (n >= N_NODES) return;
    int lane = t & 63;
    int eg = lane >> 3;
    int c  = (lane & 7) << 3;

    int beg = row[n], end = row[n + 1];
    float iv = inv[n];
    float acc[8] = {0.f, 0.f, 0.f, 0.f, 0.f, 0.f, 0.f, 0.f};
    int k = beg;
    for (; k + 16 <= end; k += 16) {
        int s0 = sorted[k + eg];
        int s1 = sorted[k + 8 + eg];
        f16x8 v0 = *(const f16x8*)(in + (size_t)s0 * DIM + c);
        f16x8 v1 = *(const f16x8*)(in + (size_t)s1 * DIM + c);
#pragma unroll
        for (int m = 0; m < 8; ++m) acc[m] += (float)v0[m] + (float)v1[m];
    }
    if (k + 8 <= end) {
        int s0 = sorted[k + eg];
        f16x8 v0 = *(const f16x8*)(in + (size_t)s0 * DIM + c);
#pragma unroll
        for (int m = 0; m < 8; ++m) acc[m] += (float)v0[m];
        k += 8;
    }
    if (k + eg < end) {
        f16x8 v0 = *(const f16x8*)(in + (size_t)sorted[k + eg] * DIM + c);
#pragma unroll
        for (int m = 0; m < 8; ++m) acc[m] += (float)v0[m];
    }
#pragma unroll
    for (int m = 0; m < 8; ++m) {
        acc[m] += __shfl_xor(acc[m], 8, 64);
        acc[m] += __shfl_xor(acc[m], 16, 64);
        acc[m] += __shfl_xor(acc[m], 32, 64);
    }
    if (eg == 0) {
        f16x8 r;
#pragma unroll
        for (int m = 0; m < 8; ++m) r[m] = (f16)(acc[m] * iv);
        *(f16x8*)(out + (size_t)n * DIM + c) = r;
    }
}

// ---------------- W -> MFMA B-fragment layout (fp16), 4 matrices ----------------
__global__ void wfrag_kernel(const float* __restrict__ W0, const float* __restrict__ W1,
                             f16* __restrict__ wfrag) {
    int mat = blockIdx.x;
    const float* W = (mat & 2) ? W1 : W0;
    if (mat & 1) W += DIM * DIM;
    int t = threadIdx.x;
    for (int idx = t; idx < 4096; idx += 256) {
        int ct = idx >> 10, kk = (idx >> 9) & 1, l = (idx >> 3) & 63, i = idx & 7;
        int k = kk * 32 + (l >> 4) * 8 + i;
        int col = ct * 16 + (l & 15);
        wfrag[mat * 4096 + idx] = (f16)W[k * DIM + col];
    }
}

// ---------------- MFMA GEMM: out = relu(A @ W + b), fp16 in/out ----------------
__global__ void gemm_kernel(const __half* __restrict__ A_a, const f16* __restrict__ wf_a,
                            const float* __restrict__ bias_a, __half* __restrict__ out_a,
                            const __half* __restrict__ A_b, const f16* __restrict__ wf_b,
                            const float* __restrict__ bias_b, __half* __restrict__ out_b) {
    const f16* A; const f16* wf; const float* bias; f16* out;
    if (blockIdx.y == 0) { A = (const f16*)A_a; wf = wf_a; bias = bias_a; out = (f16*)out_a; }
    else                 { A = (const f16*)A_b; wf = wf_b; bias = bias_b; out = (f16*)out_b; }

    int t = threadIdx.x, w = t >> 6, l = t & 63;
    int tile = blockIdx.x * 4 + w;
    if (tile >= NTILES) return;
    int g = l >> 4, c = l & 15;

    const f16* arow = A + ((size_t)tile * 16 + c) * DIM + 8 * g;
    f16x8 a0 = *(const f16x8*)(arow);
    f16x8 a1 = *(const f16x8*)(arow + 32);

#pragma unroll
    for (int ct = 0; ct < 4; ++ct) {
        f16x8 b0 = *(const f16x8*)(wf + ((ct * 2 + 0) * 64 + l) * 8);
        f16x8 b1 = *(const f16x8*)(wf + ((ct * 2 + 1) * 64 + l) * 8);
        f32x4 acc = {0.f, 0.f, 0.f, 0.f};
        acc = __builtin_amdgcn_mfma_f32_16x16x32_f16(a0, b0, acc, 0, 0, 0);
        acc = __builtin_amdgcn_mfma_f32_16x16x32_f16(a1, b1, acc, 0, 0, 0);
        float bs = bias[ct * 16 + c];
#pragma unroll
        for (int i = 0; i < 4; ++i) {
            float v = fmaxf(acc[i] + bs, 0.0f);
            out[((size_t)tile * 16 + 4 * g + i) * DIM + ct * 16 + c] = (f16)v;
        }
    }
}

// ---------------- per-graph projection ----------------
__global__ void graph_proj_kernel(const __half* __restrict__ x0, const __half* __restrict__ x1,
                                  const float* __restrict__ Wout, const float* __restrict__ bout,
                                  const int* __restrict__ batch, float* __restrict__ out) {
    int g = blockIdx.x;
    __shared__ int bounds[2];
    __shared__ float hs[4][DIM];
    int t = threadIdx.x;
    if (t < 2) {
        int target = g + t;
        int lo = 0, hi = N_NODES;
        while (lo < hi) { int mid = (lo + hi) >> 1; if (batch[mid] < target) lo = mid + 1; else hi = mid; }
        bounds[t] = lo;
    }
    __syncthreads();
    int beg = bounds[0], end = bounds[1];
    int w = t >> 6, j = t & 63;
    float s = 0.0f;
    for (int n = beg + w; n < end; n += 4)
        s += __half2float(x0[(size_t)n * DIM + j]) + __half2float(x1[(size_t)n * DIM + j]);
    hs[w][j] = s;
    __syncthreads();
    if (t < DIM) hs[0][t] = (hs[0][t] + hs[1][t] + hs[2][t] + hs[3][t]) * 0.5f;
    __syncthreads();
    if (t < N_CLASS) {
        int cnt = end - beg;
        float acc = 0.0f;
#pragma unroll
        for (int d = 0; d < DIM; ++d) acc += hs[0][d] * Wout[d * N_CLASS + t];
        out[g * N_CLASS + t] = (cnt > 0) ? (acc / (float)cnt + bout[t]) : 0.0f;
    }
}

extern "C" void kernel_launch(void* const* d_in, const int* in_sizes, int n_in,
                              void* d_out, int out_size, void* d_ws, size_t ws_size,
                              hipStream_t stream) {
    const float* x    = (const float*)d_in[0];
    const float* W0   = (const float*)d_in[1];
    const float* b0   = (const float*)d_in[2];
    const float* W1   = (const float*)d_in[3];
    const float* b1   = (const float*)d_in[4];
    const float* Wout = (const float*)d_in[5];
    const float* bout = (const float*)d_in[6];
    const int* ei_sc  = (const int*)d_in[7];
    const int* ei_fc  = (const int*)d_in[8];
    const int* batch  = (const int*)d_in[9];

    const int* src_sc = ei_sc;
    const int* dst_sc = ei_sc + N_EDGES;
    const int* src_fc = ei_fc;
    const int* dst_fc = ei_fc + N_EDGES;

    // ---- workspace layout (byte-based) ----
    char* ws = (char*)d_ws;
    size_t off = 0;
    auto alloc = [&](size_t bytes) { void* p = ws + off; off += (bytes + 15) & ~size_t(15); return p; };
    __half* xh   = (__half*)alloc((size_t)N_NODES * DIM * 2);
    __half* As_  = (__half*)alloc((size_t)N_NODES * DIM * 2);  // agg sc  | aliased: cnt_sc
    __half* Af_  = (__half*)alloc((size_t)N_NODES * DIM * 2);  // agg fc  | aliased: cnt_fc
    __half* Hs_  = (__half*)alloc((size_t)N_NODES * DIM * 2);  // hidden sc | aliased: base_sc
    __half* Hf_  = (__half*)alloc((size_t)N_NODES * DIM * 2);  // hidden fc | aliased: base_fc
    f16*   wfrag = (f16*)alloc(4 * 4096 * 2);
    float* inv_sc = (float*)alloc(N_NODES * 4);
    float* inv_fc = (float*)alloc(N_NODES * 4);
    int*   deg_sc = (int*)alloc(N_NODES * 4);
    int*   deg_fc = (int*)alloc(N_NODES * 4);
    int*   row_sc = (int*)alloc((N_NODES + 1) * 4);
    int*   row_fc = (int*)alloc((N_NODES + 1) * 4);
    int*   partial = (int*)alloc(2 * NSCB * 4);
    unsigned short* rank_sc = (unsigned short*)alloc((size_t)N_EDGES * 2);
    unsigned short* rank_fc = (unsigned short*)alloc((size_t)N_EDGES * 2);
    unsigned short* sorted_sc = (unsigned short*)alloc((size_t)N_EDGES * 2);
    unsigned short* sorted_fc = (unsigned short*)alloc((size_t)N_EDGES * 2);

    // CSR-build scratch aliased onto layer buffers (dead until agg/gemm):
    unsigned int*   cnt_sc  = (unsigned int*)As_;    // NB*NHALF dwords = 6.4 MB
    unsigned int*   cnt_fc  = (unsigned int*)Af_;
    unsigned short* base_sc = (unsigned short*)Hs_;  // NB*N ushort = 6.4 MB
    unsigned short* base_fc = (unsigned short*)Hf_;

    const int BLK = 256;
    dim3 blk(BLK);
    int grid_E  = (N_EDGES + BLK - 1) / BLK;
    int grid_N4 = (N_NODES + 3) / 4;
    int grid_N  = (N_NODES + BLK - 1) / BLK;
    int grid_G  = (NTILES + 3) / 4;

    // ---- CSR build (no global atomics anywhere) + x->fp16 + W fragments ----
    conv_kernel<<<grid_E, blk, 0, stream>>>(x, xh);
    wfrag_kernel<<<4, blk, 0, stream>>>(W0, W1, wfrag);
    hist_kernel<<<dim3(NB, 2), 1024, NHALF * sizeof(unsigned int), stream>>>(
        dst_sc, dst_fc, rank_sc, rank_fc, cnt_sc, cnt_fc);
    combine_kernel<<<dim3(grid_N, 2), blk, 0, stream>>>(cnt_sc, cnt_fc,
                                                        base_sc, base_fc,
                                                        deg_sc, deg_fc);
    scanA_kernel<<<dim3(NSCB, 2), blk, 0, stream>>>(deg_sc, deg_fc, partial);
    scanB_kernel<<<1, 64, 0, stream>>>(partial);
    scanC_kernel<<<dim3(NSCB, 2), blk, 0, stream>>>(deg_sc, deg_fc, partial,
                                                    row_sc, row_fc, inv_sc, inv_fc);
    fill3_kernel<<<dim3(grid_E, 2), blk, 0, stream>>>(
        src_sc, dst_sc, rank_sc, row_sc, base_sc, sorted_sc,
        src_fc, dst_fc, rank_fc, row_fc, base_fc, sorted_fc);

    // ---- layer 0: agg (xh -> As,Af), gemm (-> Hs,Hf) ----
    agg_kernel<<<dim3(grid_N4, 2), blk, 0, stream>>>(
        row_sc, sorted_sc, inv_sc, xh, As_,
        row_fc, sorted_fc, inv_fc, xh, Af_);
    gemm_kernel<<<dim3(grid_G, 2), blk, 0, stream>>>(
        As_, wfrag + 0 * 4096, b0, Hs_,
        Af_, wfrag + 2 * 4096, b1, Hf_);

    // ---- layer 1: agg (Hs,Hf -> As,Af), gemm (-> Hs,Hf) ----
    agg_kernel<<<dim3(grid_N4, 2), blk, 0, stream>>>(
        row_sc, sorted_sc, inv_sc, Hs_, As_,
        row_fc, sorted_fc, inv_fc, Hf_, Af_);
    gemm_kernel<<<dim3(grid_G, 2), blk, 0, stream>>>(
        As_, wfrag + 1 * 4096, b0 + DIM, Hs_,
        Af_, wfrag + 3 * 4096, b1 + DIM, Hf_);

    // ---- per-graph projection ----
    graph_proj_kernel<<<N_GRAPH, blk, 0, stream>>>(Hs_, Hf_, Wout, bout, batch,
                                                   (float*)d_out);
}